// Round 1
// baseline (788.992 us; speedup 1.0000x reference)
//
#include <hip/hip_runtime.h>
#include <hip/hip_bf16.h>
#include <stdint.h>

typedef short short8 __attribute__((ext_vector_type(8)));   // 8 bf16 (4 VGPRs)
typedef float f32x4 __attribute__((ext_vector_type(4)));

#define NSAMP 65536

__device__ __forceinline__ unsigned short f2bf(float f) {
    union { float f; unsigned u; } v; v.f = f;
    unsigned u = v.u;
    u += 0x7fffu + ((u >> 16) & 1u);   // round-to-nearest-even
    return (unsigned short)(u >> 16);
}

// ---------------- prep kernels ----------------

__global__ void k_convert_bf16(const float* __restrict__ in, unsigned short* __restrict__ out, int n8) {
    int i = blockIdx.x * blockDim.x + threadIdx.x;
    if (i >= n8) return;
    const float4* p = (const float4*)in + (size_t)i * 2;
    float4 a = p[0], b = p[1];
    short8 o;
    o[0] = (short)f2bf(a.x); o[1] = (short)f2bf(a.y);
    o[2] = (short)f2bf(a.z); o[3] = (short)f2bf(a.w);
    o[4] = (short)f2bf(b.x); o[5] = (short)f2bf(b.y);
    o[6] = (short)f2bf(b.z); o[7] = (short)f2bf(b.w);
    ((short8*)out)[i] = o;
}

// W [K][N] fp32  ->  WT [N][K] bf16
__global__ void k_transpose_bf16(const float* __restrict__ W, unsigned short* __restrict__ WT, int K, int N) {
    int i = blockIdx.x * blockDim.x + threadIdx.x;
    if (i >= K * N) return;
    int k = i / N, n = i - k * N;
    WT[(size_t)n * K + k] = f2bf(W[i]);
}

__global__ void k_zero(float* p, int n) {
    int i = blockIdx.x * blockDim.x + threadIdx.x;
    if (i < n) p[i] = 0.f;
}

__global__ void k_select(const float* __restrict__ y0, const float* __restrict__ y1,
                         const int* __restrict__ t, float* __restrict__ y, int n) {
    int i = blockIdx.x * blockDim.x + threadIdx.x;
    if (i < n) y[i] = (t[i] == 0) ? y0[i] : y1[i];
}

// ---------------- GEMM ----------------
// C[M][Ncols] = A[M][K] * BT[Ncols][K]^T + bias
// MODE 0: relu -> bf16 store
// MODE 1: no relu -> fp32 store + bf16 store
// MODE 2: relu, then fused dot: atomicAdd(ydot[m], sum_n relu(..)[m][n]*w2[n]); no C store
// 128x128 tile, BK=64, 4 waves (2x2 of 64x64), 16x16x32 bf16 MFMA.
// LDS layout: A tile [128][64] bf16 (16KB), B tile same. XOR swizzle: 16B chunk
// slot c holds data chunk (c ^ (row&7)); achieved by pre-swizzling the GLOBAL
// source for global_load_lds (linear LDS write), un-swizzled on ds_read side.
template<int MODE>
__global__ __launch_bounds__(256)
void k_gemm(const unsigned short* __restrict__ A,
            const unsigned short* __restrict__ BT,
            const float* __restrict__ bias,
            unsigned short* __restrict__ Cbf,
            float* __restrict__ Cf32,
            const float* __restrict__ w2,
            float* __restrict__ ydot,
            int Ncols, int K)
{
    __shared__ __align__(16) char lds[2 * 128 * 64 * 2];   // A at 0, B at 16384
    char* ldsA = lds;
    char* ldsB = lds + 128 * 64 * 2;

    const int tid  = threadIdx.x;
    const int lane = tid & 63;
    const int wid  = tid >> 6;
    const int wr = wid >> 1, wc = wid & 1;
    const int m0 = blockIdx.x * 128;
    const int n0 = blockIdx.y * 128;

    f32x4 acc[4][4];
#pragma unroll
    for (int i = 0; i < 4; ++i)
#pragma unroll
        for (int j = 0; j < 4; ++j) acc[i][j] = (f32x4)0.f;

    const int KT = K >> 6;   // K / 64
    for (int kt = 0; kt < KT; ++kt) {
        const int k0 = kt << 6;
        __syncthreads();   // previous tile's compute done before overwrite
#pragma unroll
        for (int q = 0; q < 4; ++q) {
            int e   = q * 256 + tid;
            int row = e >> 3;          // 0..127 over q
            int c   = tid & 7;         // 16B chunk slot within 128B row
            int cs  = c ^ (row & 7);   // pre-swizzled source chunk
            const unsigned short* ga = A  + (size_t)(m0 + row) * K + k0 + cs * 8;
            const unsigned short* gb = BT + (size_t)(n0 + row) * K + k0 + cs * 8;
            char* la = ldsA + q * 4096 + wid * 1024;   // wave-uniform base, lane*16 implicit
            char* lb = ldsB + q * 4096 + wid * 1024;
            __builtin_amdgcn_global_load_lds((const __attribute__((address_space(1))) void*)ga,
                                             (__attribute__((address_space(3))) void*)la, 16, 0, 0);
            __builtin_amdgcn_global_load_lds((const __attribute__((address_space(1))) void*)gb,
                                             (__attribute__((address_space(3))) void*)lb, 16, 0, 0);
        }
        __syncthreads();   // compiler drains vmcnt before barrier -> tiles visible
#pragma unroll
        for (int kk = 0; kk < 2; ++kk) {
            short8 af[4], bfr[4];
#pragma unroll
            for (int i = 0; i < 4; ++i) {
                int rowa = wr * 64 + i * 16 + (lane & 15);
                int ca   = (kk * 4 + (lane >> 4)) ^ (rowa & 7);
                af[i] = *(const short8*)(ldsA + rowa * 128 + (ca << 4));
                int rowb = wc * 64 + i * 16 + (lane & 15);
                int cb   = (kk * 4 + (lane >> 4)) ^ (rowb & 7);
                bfr[i] = *(const short8*)(ldsB + rowb * 128 + (cb << 4));
            }
#pragma unroll
            for (int i = 0; i < 4; ++i)
#pragma unroll
                for (int j = 0; j < 4; ++j)
                    acc[i][j] = __builtin_amdgcn_mfma_f32_16x16x32_bf16(af[i], bfr[j], acc[i][j], 0, 0, 0);
        }
    }

    // epilogue: D col = lane&15 (n), row = (lane>>4)*4 + reg (m)  [m89-verified]
    const int mbase = m0 + wr * 64 + (lane >> 4) * 4;
    const int nbase = n0 + wc * 64 + (lane & 15);

    if (MODE == 2) {
        float bv[4], wv[4];
#pragma unroll
        for (int j = 0; j < 4; ++j) {
            int ncol = nbase + j * 16;
            bv[j] = bias[ncol];
            wv[j] = w2[ncol];
        }
#pragma unroll
        for (int i = 0; i < 4; ++i) {
#pragma unroll
            for (int r = 0; r < 4; ++r) {
                float p = 0.f;
#pragma unroll
                for (int j = 0; j < 4; ++j) {
                    float v = fmaxf(acc[i][j][r] + bv[j], 0.f);
                    p += v * wv[j];
                }
                p += __shfl_xor(p, 1);
                p += __shfl_xor(p, 2);
                p += __shfl_xor(p, 4);
                p += __shfl_xor(p, 8);
                if ((lane & 15) == 0) {
                    atomicAdd(&ydot[mbase + i * 16 + r], p);
                }
            }
        }
    } else {
        float bv[4];
#pragma unroll
        for (int j = 0; j < 4; ++j) bv[j] = bias[nbase + j * 16];
#pragma unroll
        for (int i = 0; i < 4; ++i) {
#pragma unroll
            for (int j = 0; j < 4; ++j) {
                int ncol = nbase + j * 16;
#pragma unroll
                for (int r = 0; r < 4; ++r) {
                    float v = acc[i][j][r] + bv[j];
                    if (MODE == 0) v = fmaxf(v, 0.f);
                    size_t idx = (size_t)(mbase + i * 16 + r) * Ncols + ncol;
                    if (MODE == 1) Cf32[idx] = v;
                    Cbf[idx] = f2bf(v);
                }
            }
        }
    }
}

// ---------------- launch ----------------

extern "C" void kernel_launch(void* const* d_in, const int* in_sizes, int n_in,
                              void* d_out, int out_size, void* d_ws, size_t ws_size,
                              hipStream_t stream) {
    const float* X   = (const float*)d_in[0];
    const int*  TR   = (const int*)d_in[1];
    const float* W0 = (const float*)d_in[2];  const float* b0 = (const float*)d_in[3];
    const float* W1 = (const float*)d_in[4];  const float* b1 = (const float*)d_in[5];
    const float* W2 = (const float*)d_in[6];  const float* b2 = (const float*)d_in[7];
    const float* A0 = (const float*)d_in[8];  const float* a0 = (const float*)d_in[9];
    const float* A1 = (const float*)d_in[10]; const float* a1 = (const float*)d_in[11];
    const float* A2 = (const float*)d_in[12];
    const float* C0 = (const float*)d_in[13]; const float* c0 = (const float*)d_in[14];
    const float* C1 = (const float*)d_in[15]; const float* c1 = (const float*)d_in[16];
    const float* C2 = (const float*)d_in[17];

    float* y_out   = (float*)d_out;           // [N]
    float* out_out = (float*)d_out + NSAMP;   // [N][512]

    char* ws = (char*)d_ws;
    size_t off = 0;
    auto alloc = [&](size_t bytes) -> char* {
        char* p = ws + off;
        off += (bytes + 255) & ~(size_t)255;
        return p;
    };
    unsigned short* Xb  = (unsigned short*)alloc((size_t)NSAMP * 512 * 2);
    unsigned short* H1  = (unsigned short*)alloc((size_t)NSAMP * 1024 * 2);
    unsigned short* H2  = (unsigned short*)alloc((size_t)NSAMP * 1024 * 2);
    unsigned short* OUTb = H1;                              // H1 dead after L1 GEMM
    unsigned short* R0  = H2;                               // H2 dead after OUT GEMM
    unsigned short* R1  = H2 + (size_t)NSAMP * 512;
    unsigned short* W0T = (unsigned short*)alloc(512 * 1024 * 2);
    unsigned short* W1T = (unsigned short*)alloc(1024 * 1024 * 2);
    unsigned short* W2T = (unsigned short*)alloc(1024 * 512 * 2);
    unsigned short* A0T = (unsigned short*)alloc(512 * 512 * 2);
    unsigned short* A1T = (unsigned short*)alloc(512 * 512 * 2);
    unsigned short* C0T = (unsigned short*)alloc(512 * 512 * 2);
    unsigned short* C1T = (unsigned short*)alloc(512 * 512 * 2);
    float* y0 = (float*)alloc(NSAMP * 4);
    float* y1 = (float*)alloc(NSAMP * 4);

    // prep: input conversion, weight transposes, dot-accumulator zero
    k_convert_bf16<<<(NSAMP * 512 / 8 + 255) / 256, 256, 0, stream>>>(X, Xb, NSAMP * 512 / 8);
    k_transpose_bf16<<<(512 * 1024 + 255) / 256, 256, 0, stream>>>(W0, W0T, 512, 1024);
    k_transpose_bf16<<<(1024 * 1024 + 255) / 256, 256, 0, stream>>>(W1, W1T, 1024, 1024);
    k_transpose_bf16<<<(1024 * 512 + 255) / 256, 256, 0, stream>>>(W2, W2T, 1024, 512);
    k_transpose_bf16<<<(512 * 512 + 255) / 256, 256, 0, stream>>>(A0, A0T, 512, 512);
    k_transpose_bf16<<<(512 * 512 + 255) / 256, 256, 0, stream>>>(A1, A1T, 512, 512);
    k_transpose_bf16<<<(512 * 512 + 255) / 256, 256, 0, stream>>>(C0, C0T, 512, 512);
    k_transpose_bf16<<<(512 * 512 + 255) / 256, 256, 0, stream>>>(C1, C1T, 512, 512);
    k_zero<<<(NSAMP + 255) / 256, 256, 0, stream>>>(y0, NSAMP);
    k_zero<<<(NSAMP + 255) / 256, 256, 0, stream>>>(y1, NSAMP);

    const int MB = NSAMP / 128;   // 512

    // shared MLP
    k_gemm<0><<<dim3(MB, 8), 256, 0, stream>>>(Xb, W0T, b0, H1, nullptr, nullptr, nullptr, 1024, 512);
    k_gemm<0><<<dim3(MB, 8), 256, 0, stream>>>(H1, W1T, b1, H2, nullptr, nullptr, nullptr, 1024, 1024);
    k_gemm<1><<<dim3(MB, 4), 256, 0, stream>>>(H2, W2T, b2, OUTb, out_out, nullptr, nullptr, 512, 1024);

    // risk nets, layer 0 (both experts, dense)
    k_gemm<0><<<dim3(MB, 4), 256, 0, stream>>>(OUTb, A0T, a0, R0, nullptr, nullptr, nullptr, 512, 512);
    k_gemm<0><<<dim3(MB, 4), 256, 0, stream>>>(OUTb, C0T, c0, R1, nullptr, nullptr, nullptr, 512, 512);

    // risk nets, layer 1 + fused 512->1 dot
    k_gemm<2><<<dim3(MB, 4), 256, 0, stream>>>(R0, A1T, a1, nullptr, nullptr, A2, y0, 512, 512);
    k_gemm<2><<<dim3(MB, 4), 256, 0, stream>>>(R1, C1T, c1, nullptr, nullptr, C2, y1, 512, 512);

    // per-sample expert selection
    k_select<<<(NSAMP + 255) / 256, 256, 0, stream>>>(y0, y1, TR, y_out, NSAMP);
}

// Round 2
// 578.009 us; speedup vs baseline: 1.3650x; 1.3650x over previous
//
#include <hip/hip_runtime.h>
#include <hip/hip_bf16.h>
#include <stdint.h>

typedef short short8 __attribute__((ext_vector_type(8)));   // 8 bf16 (4 VGPRs)
typedef float f32x4 __attribute__((ext_vector_type(4)));

#define NSAMP 65536

__device__ __forceinline__ unsigned short f2bf(float f) {
    union { float f; unsigned u; } v; v.f = f;
    unsigned u = v.u;
    u += 0x7fffu + ((u >> 16) & 1u);   // round-to-nearest-even
    return (unsigned short)(u >> 16);
}

// ---------------- prep kernels ----------------

__global__ void k_convert_bf16(const float* __restrict__ in, unsigned short* __restrict__ out, int n8) {
    int i = blockIdx.x * blockDim.x + threadIdx.x;
    if (i >= n8) return;
    const float4* p = (const float4*)in + (size_t)i * 2;
    float4 a = p[0], b = p[1];
    short8 o;
    o[0] = (short)f2bf(a.x); o[1] = (short)f2bf(a.y);
    o[2] = (short)f2bf(a.z); o[3] = (short)f2bf(a.w);
    o[4] = (short)f2bf(b.x); o[5] = (short)f2bf(b.y);
    o[6] = (short)f2bf(b.z); o[7] = (short)f2bf(b.w);
    ((short8*)out)[i] = o;
}

// All weight transposes (fp32 [K][N] -> bf16 [N][K]) + bias concat + y0/y1 zero, fused.
struct PrepArgs {
    const float *W0, *W1, *W2, *A0, *C0, *A1, *C1, *a0v, *c0v;
    unsigned short *W0T, *W1T, *W2T, *RT0, *A1T, *C1T;
    float *bcat, *y0, *y1;
};
__global__ void k_prep(PrepArgs p) {
    int i = blockIdx.x * blockDim.x + threadIdx.x;
    if (i < 524288)  { int k = i >> 10, n = i & 1023; p.W0T[n * 512 + k] = f2bf(p.W0[i]); return; }
    i -= 524288;
    if (i < 1048576) { int k = i >> 10, n = i & 1023; p.W1T[n * 1024 + k] = f2bf(p.W1[i]); return; }
    i -= 1048576;
    if (i < 524288)  { int k = i >> 9, n = i & 511; p.W2T[n * 1024 + k] = f2bf(p.W2[i]); return; }
    i -= 524288;
    if (i < 262144)  { int k = i >> 9, n = i & 511; p.RT0[n * 512 + k] = f2bf(p.A0[i]); return; }
    i -= 262144;
    if (i < 262144)  { int k = i >> 9, n = i & 511; p.RT0[(512 + n) * 512 + k] = f2bf(p.C0[i]); return; }
    i -= 262144;
    if (i < 262144)  { int k = i >> 9, n = i & 511; p.A1T[n * 512 + k] = f2bf(p.A1[i]); return; }
    i -= 262144;
    if (i < 262144)  { int k = i >> 9, n = i & 511; p.C1T[n * 512 + k] = f2bf(p.C1[i]); return; }
    i -= 262144;
    if (i < 512)     { p.bcat[i] = p.a0v[i]; return; }
    i -= 512;
    if (i < 512)     { p.bcat[512 + i] = p.c0v[i]; return; }
    i -= 512;
    if (i < 65536)   { p.y0[i] = 0.f; return; }
    i -= 65536;
    if (i < 65536)   { p.y1[i] = 0.f; return; }
}

__global__ void k_select(const float* __restrict__ y0, const float* __restrict__ y1,
                         const int* __restrict__ t, float* __restrict__ y, int n) {
    int i = blockIdx.x * blockDim.x + threadIdx.x;
    if (i < n) y[i] = (t[i] == 0) ? y0[i] : y1[i];
}

// ---------------- GEMM: 256x256 tile, BK=64, 8 waves, 2-deep counted-vmcnt pipeline ----
// C[M][Ncols] = A[M][K](lda,colOff) * BT[Ncols][K]^T + bias
// MODE 0: relu -> bf16 store
// MODE 1: no relu -> fp32 store + bf16 store
// MODE 2: relu, then fused dot: atomicAdd(ydot[m], sum_n relu(..)[m][n] * w2[n]); no C store
//
// LDS 128 KiB: buf[2] x { A[256][64] bf16 (32KB), B[256][64] (32KB) }.
// XOR swizzle (T2): 16B chunk slot c of row r holds data chunk c^(r&7); achieved by
// pre-swizzling the GLOBAL source (global_load_lds writes linearly), un-XOR on ds_read.
// Schedule (T3/T4): raw s_barrier + counted vmcnt(8); tile t+2's loads issue after the
// barrier certifying buf[t&1] fully consumed; tile-boundary wait leaves those 8 in flight.
template<int MODE>
__global__ __launch_bounds__(512, 2)
void k_gemm256(const unsigned short* __restrict__ A, int lda, int colOff,
               const unsigned short* __restrict__ BT,
               const float* __restrict__ bias,
               unsigned short* __restrict__ Cbf,
               float* __restrict__ Cf32,
               const float* __restrict__ w2,
               float* __restrict__ ydot,
               int Ncols, int K, int NB)
{
    __shared__ __align__(16) char lds[131072];

    const int tid  = threadIdx.x;
    const int lane = tid & 63;
    const int wid  = tid >> 6;       // 0..7
    const int wr   = wid >> 2;       // 0..1  -> A rows [wr*128, +128)
    const int wcn  = wid & 3;        // 0..3  -> B cols [wcn*64, +64)

    // T1: bijective XCD swizzle (nwg % 8 == 0 for all our shapes), N-tile fastest.
    const int nwg = gridDim.x;
    const int bid = blockIdx.x;
    const int swz = (bid & 7) * (nwg >> 3) + (bid >> 3);
    const int mt = swz / NB, nt = swz % NB;
    const int m0 = mt << 8, n0 = nt << 8;

    auto stage = [&](int t, int pb) {
        const int k0 = t << 6;
        char* dA = lds + pb * 65536;
        char* dB = dA + 32768;
#pragma unroll
        for (int q = 0; q < 4; ++q) {
            int chunk = q * 512 + tid;                 // 0..2047
            int row = chunk >> 3;
            int cs  = (chunk & 7) ^ (row & 7);         // pre-swizzled source chunk
            const unsigned short* ga = A + (size_t)(m0 + row) * lda + colOff + k0 + cs * 8;
            char* la = dA + q * 8192 + wid * 1024;     // wave-uniform base (+lane*16 implicit)
            __builtin_amdgcn_global_load_lds((const __attribute__((address_space(1))) void*)ga,
                                             (__attribute__((address_space(3))) void*)la, 16, 0, 0);
        }
#pragma unroll
        for (int q = 0; q < 4; ++q) {
            int chunk = q * 512 + tid;
            int row = chunk >> 3;
            int cs  = (chunk & 7) ^ (row & 7);
            const unsigned short* gb = BT + (size_t)(n0 + row) * K + k0 + cs * 8;
            char* lb = dB + q * 8192 + wid * 1024;
            __builtin_amdgcn_global_load_lds((const __attribute__((address_space(1))) void*)gb,
                                             (__attribute__((address_space(3))) void*)lb, 16, 0, 0);
        }
    };

    f32x4 acc[8][4];
#pragma unroll
    for (int i = 0; i < 8; ++i)
#pragma unroll
        for (int j = 0; j < 4; ++j) acc[i][j] = (f32x4)0.f;

    const int KT = K >> 6;           // >= 8 for all our shapes

    stage(0, 0);
    stage(1, 1);
    asm volatile("s_waitcnt vmcnt(8)" ::: "memory");   // tile 0 landed (my 8); tile 1 in flight
    __builtin_amdgcn_s_barrier();                      // all waves' tile-0 shares landed
    __builtin_amdgcn_sched_barrier(0);

    for (int t = 0; t < KT; ++t) {
        const char* sA = lds + (t & 1) * 65536;
        const char* sB = sA + 32768;
#pragma unroll
        for (int kk = 0; kk < 2; ++kk) {
            short8 af[8], bfv[4];
#pragma unroll
            for (int i = 0; i < 8; ++i) {
                int r = wr * 128 + i * 16 + (lane & 15);
                int c = (kk * 4 + (lane >> 4)) ^ (r & 7);
                af[i] = *(const short8*)(sA + r * 128 + c * 16);
            }
#pragma unroll
            for (int j = 0; j < 4; ++j) {
                int r = wcn * 64 + j * 16 + (lane & 15);
                int c = (kk * 4 + (lane >> 4)) ^ (r & 7);
                bfv[j] = *(const short8*)(sB + r * 128 + c * 16);
            }
            __builtin_amdgcn_s_setprio(1);
#pragma unroll
            for (int i = 0; i < 8; ++i)
#pragma unroll
                for (int j = 0; j < 4; ++j)
                    acc[i][j] = __builtin_amdgcn_mfma_f32_16x16x32_bf16(af[i], bfv[j], acc[i][j], 0, 0, 0);
            __builtin_amdgcn_s_setprio(0);
        }
        if (t + 1 < KT) {
            __builtin_amdgcn_s_barrier();              // all reads of buf[t&1] done
            if (t + 2 < KT) {
                stage(t + 2, t & 1);                   // overwrite consumed buffer
                asm volatile("s_waitcnt vmcnt(8)" ::: "memory");  // tile t+1 landed; t+2 in flight
            } else {
                asm volatile("s_waitcnt vmcnt(0)" ::: "memory");  // drain: last tile landed
            }
            __builtin_amdgcn_s_barrier();              // buf[(t+1)&1] staged for all waves
            __builtin_amdgcn_sched_barrier(0);
        }
    }

    // epilogue: D col = lane&15 (n), row = (lane>>4)*4 + reg (m)  [m89-verified, r1-passed]
    const int mbase = m0 + wr * 128 + (lane >> 4) * 4;
    const int nbase = n0 + wcn * 64 + (lane & 15);

    if (MODE == 2) {
        float bv[4], wv[4];
#pragma unroll
        for (int j = 0; j < 4; ++j) {
            int ncol = nbase + j * 16;
            bv[j] = bias[ncol];
            wv[j] = w2[ncol];
        }
#pragma unroll
        for (int i = 0; i < 8; ++i) {
#pragma unroll
            for (int r = 0; r < 4; ++r) {
                float p = 0.f;
#pragma unroll
                for (int j = 0; j < 4; ++j) {
                    float v = fmaxf(acc[i][j][r] + bv[j], 0.f);
                    p += v * wv[j];
                }
                p += __shfl_xor(p, 1);
                p += __shfl_xor(p, 2);
                p += __shfl_xor(p, 4);
                p += __shfl_xor(p, 8);
                if ((lane & 15) == 0) {
                    atomicAdd(&ydot[mbase + i * 16 + r], p);
                }
            }
        }
    } else {
        float bv[4];
#pragma unroll
        for (int j = 0; j < 4; ++j) bv[j] = bias[nbase + j * 16];
#pragma unroll
        for (int i = 0; i < 8; ++i) {
#pragma unroll
            for (int j = 0; j < 4; ++j) {
                int ncol = nbase + j * 16;
#pragma unroll
                for (int r = 0; r < 4; ++r) {
                    float v = acc[i][j][r] + bv[j];
                    if (MODE == 0) v = fmaxf(v, 0.f);
                    size_t idx = (size_t)(mbase + i * 16 + r) * Ncols + ncol;
                    if (MODE == 1) Cf32[idx] = v;
                    Cbf[idx] = f2bf(v);
                }
            }
        }
    }
}

// ---------------- launch ----------------

extern "C" void kernel_launch(void* const* d_in, const int* in_sizes, int n_in,
                              void* d_out, int out_size, void* d_ws, size_t ws_size,
                              hipStream_t stream) {
    const float* X  = (const float*)d_in[0];
    const int*  TR  = (const int*)d_in[1];
    const float* W0 = (const float*)d_in[2];  const float* b0 = (const float*)d_in[3];
    const float* W1 = (const float*)d_in[4];  const float* b1 = (const float*)d_in[5];
    const float* W2 = (const float*)d_in[6];  const float* b2 = (const float*)d_in[7];
    const float* A0 = (const float*)d_in[8];  const float* a0 = (const float*)d_in[9];
    const float* A1 = (const float*)d_in[10]; const float* a1 = (const float*)d_in[11];
    const float* A2 = (const float*)d_in[12];
    const float* C0 = (const float*)d_in[13]; const float* c0 = (const float*)d_in[14];
    const float* C1 = (const float*)d_in[15]; const float* c1 = (const float*)d_in[16];
    const float* C2 = (const float*)d_in[17];

    float* y_out   = (float*)d_out;           // [N]
    float* out_out = (float*)d_out + NSAMP;   // [N][512] fp32

    char* ws = (char*)d_ws;
    size_t off = 0;
    auto alloc = [&](size_t bytes) -> char* {
        char* p = ws + off;
        off += (bytes + 255) & ~(size_t)255;
        return p;
    };
    unsigned short* Xb  = (unsigned short*)alloc((size_t)NSAMP * 512 * 2);
    unsigned short* H1b = (unsigned short*)alloc((size_t)NSAMP * 1024 * 2);
    unsigned short* H2b = (unsigned short*)alloc((size_t)NSAMP * 1024 * 2);
    unsigned short* OUTb = H1b;                       // H1b dead after L1 GEMM
    unsigned short* R01  = H2b;                       // [N][1024]: cols 0-511 expert0, 512-1023 expert1
    unsigned short* W0T = (unsigned short*)alloc(512 * 1024 * 2);
    unsigned short* W1T = (unsigned short*)alloc(1024 * 1024 * 2);
    unsigned short* W2T = (unsigned short*)alloc(1024 * 512 * 2);
    unsigned short* RT0 = (unsigned short*)alloc(1024 * 512 * 2);   // [A0T; C0T]
    unsigned short* A1T = (unsigned short*)alloc(512 * 512 * 2);
    unsigned short* C1T = (unsigned short*)alloc(512 * 512 * 2);
    float* bcat = (float*)alloc(1024 * 4);
    float* y0 = (float*)alloc(NSAMP * 4);
    float* y1 = (float*)alloc(NSAMP * 4);

    // prep
    k_convert_bf16<<<(NSAMP * 512 / 8 + 255) / 256, 256, 0, stream>>>(X, Xb, NSAMP * 512 / 8);
    PrepArgs pa;
    pa.W0 = W0; pa.W1 = W1; pa.W2 = W2; pa.A0 = A0; pa.C0 = C0; pa.A1 = A1; pa.C1 = C1;
    pa.a0v = a0; pa.c0v = c0;
    pa.W0T = W0T; pa.W1T = W1T; pa.W2T = W2T; pa.RT0 = RT0; pa.A1T = A1T; pa.C1T = C1T;
    pa.bcat = bcat; pa.y0 = y0; pa.y1 = y1;
    k_prep<<<(3277824 + 255) / 256, 256, 0, stream>>>(pa);

    const int MB = NSAMP / 256;   // 256 M-tiles

    // shared MLP
    k_gemm256<0><<<MB * 4, 512, 0, stream>>>(Xb, 512, 0, W0T, b0, H1b, nullptr, nullptr, nullptr, 1024, 512, 4);
    k_gemm256<0><<<MB * 4, 512, 0, stream>>>(H1b, 1024, 0, W1T, b1, H2b, nullptr, nullptr, nullptr, 1024, 1024, 4);
    k_gemm256<1><<<MB * 2, 512, 0, stream>>>(H2b, 1024, 0, W2T, b2, OUTb, out_out, nullptr, nullptr, 512, 1024, 2);

    // risk nets layer 0, both experts merged (N=1024)
    k_gemm256<0><<<MB * 4, 512, 0, stream>>>(OUTb, 512, 0, RT0, bcat, R01, nullptr, nullptr, nullptr, 1024, 512, 4);

    // risk nets layer 1 + fused 512->1 dot
    k_gemm256<2><<<MB * 2, 512, 0, stream>>>(R01, 1024, 0,   A1T, a1, nullptr, nullptr, A2, y0, 512, 512, 2);
    k_gemm256<2><<<MB * 2, 512, 0, stream>>>(R01, 1024, 512, C1T, c1, nullptr, nullptr, C2, y1, 512, 512, 2);

    // per-sample expert selection
    k_select<<<(NSAMP + 255) / 256, 256, 0, stream>>>(y0, y1, TR, y_out, NSAMP);
}

// Round 3
// 568.370 us; speedup vs baseline: 1.3882x; 1.0170x over previous
//
#include <hip/hip_runtime.h>
#include <hip/hip_bf16.h>
#include <stdint.h>

typedef short short8 __attribute__((ext_vector_type(8)));   // 8 bf16 (4 VGPRs)
typedef float f32x4 __attribute__((ext_vector_type(4)));

#define NSAMP 65536
#define AS1 __attribute__((address_space(1)))
#define AS3 __attribute__((address_space(3)))

__device__ __forceinline__ unsigned short f2bf(float f) {
    union { float f; unsigned u; } v; v.f = f;
    unsigned u = v.u;
    u += 0x7fffu + ((u >> 16) & 1u);   // round-to-nearest-even
    return (unsigned short)(u >> 16);
}

// ---------------- prep kernels ----------------

__global__ void k_convert_bf16(const float* __restrict__ in, unsigned short* __restrict__ out, int n8) {
    int i = blockIdx.x * blockDim.x + threadIdx.x;
    if (i >= n8) return;
    const float4* p = (const float4*)in + (size_t)i * 2;
    float4 a = p[0], b = p[1];
    short8 o;
    o[0] = (short)f2bf(a.x); o[1] = (short)f2bf(a.y);
    o[2] = (short)f2bf(a.z); o[3] = (short)f2bf(a.w);
    o[4] = (short)f2bf(b.x); o[5] = (short)f2bf(b.y);
    o[6] = (short)f2bf(b.z); o[7] = (short)f2bf(b.w);
    ((short8*)out)[i] = o;
}

// All weight transposes (fp32 [K][N] -> bf16 [N][K]) + bias concat + y0/y1 zero, fused.
struct PrepArgs {
    const float *W0, *W1, *W2, *A0, *C0, *A1, *C1, *a0v, *c0v;
    unsigned short *W0T, *W1T, *W2T, *RT0, *A1T, *C1T;
    float *bcat, *y0, *y1;
};
__global__ void k_prep(PrepArgs p) {
    int i = blockIdx.x * blockDim.x + threadIdx.x;
    if (i < 524288)  { int k = i >> 10, n = i & 1023; p.W0T[n * 512 + k] = f2bf(p.W0[i]); return; }
    i -= 524288;
    if (i < 1048576) { int k = i >> 10, n = i & 1023; p.W1T[n * 1024 + k] = f2bf(p.W1[i]); return; }
    i -= 1048576;
    if (i < 524288)  { int k = i >> 9, n = i & 511; p.W2T[n * 1024 + k] = f2bf(p.W2[i]); return; }
    i -= 524288;
    if (i < 262144)  { int k = i >> 9, n = i & 511; p.RT0[n * 512 + k] = f2bf(p.A0[i]); return; }
    i -= 262144;
    if (i < 262144)  { int k = i >> 9, n = i & 511; p.RT0[(512 + n) * 512 + k] = f2bf(p.C0[i]); return; }
    i -= 262144;
    if (i < 262144)  { int k = i >> 9, n = i & 511; p.A1T[n * 512 + k] = f2bf(p.A1[i]); return; }
    i -= 262144;
    if (i < 262144)  { int k = i >> 9, n = i & 511; p.C1T[n * 512 + k] = f2bf(p.C1[i]); return; }
    i -= 262144;
    if (i < 512)     { p.bcat[i] = p.a0v[i]; return; }
    i -= 512;
    if (i < 512)     { p.bcat[512 + i] = p.c0v[i]; return; }
    i -= 512;
    if (i < 65536)   { p.y0[i] = 0.f; return; }
    i -= 65536;
    if (i < 65536)   { p.y1[i] = 0.f; return; }
}

__global__ void k_select(const float* __restrict__ y0, const float* __restrict__ y1,
                         const int* __restrict__ t, float* __restrict__ y, int n) {
    int i = blockIdx.x * blockDim.x + threadIdx.x;
    if (i < n) y[i] = (t[i] == 0) ? y0[i] : y1[i];
}

// ---------------- GEMM: 256x256 tile, BK=64, 8 waves, m201-style 4-phase/K-tile ----
// C[M][Ncols] = A[M][K](lda,colOff) * BT[Ncols][K]^T + bias
// MODE 0: relu -> bf16 store ; MODE 1: no relu -> fp32+bf16 store ;
// MODE 2: relu + fused dot (atomicAdd ydot[m] += sum_n relu(.)*w2[n]), no C store.
//
// LDS 128 KiB = 2 dbuf x { Ak0 | Ak1 | Bk0 | Bk1 }, each block 256 rows x 32 K-elems
// (64B rows). XOR swizzle: 16B chunk slot c of row r holds logical chunk c ^ ((r>>1)&3);
// applied by pre-swizzling the GLOBAL source (global_load_lds writes linearly), inverted
// on the ds_read side -> exactly 2-way bank aliasing (free, m136).
// Schedule: per K-tile 4 phases; phase = {ds_read 8|4 x b128 ; stage 1 half-K block
// (2 x global_load_lds) ; s_barrier ; lgkmcnt(0) ; setprio(1) 16 MFMA setprio(0) ;
// [vmcnt(4) at phases 2,4] ; s_barrier}. Stage order Ak0,Bk0,Ak1,Bk1 of tile t+1 during
// tile t; each block has >=3 phases of flight before its certification wait.
template<int MODE>
__global__ __launch_bounds__(512, 2)
void k_gemm256(const unsigned short* __restrict__ A, int lda, int colOff,
               const unsigned short* __restrict__ BT,
               const float* __restrict__ bias,
               unsigned short* __restrict__ Cbf,
               float* __restrict__ Cf32,
               const float* __restrict__ w2,
               float* __restrict__ ydot,
               int Ncols, int K, int NB)
{
    __shared__ __align__(16) char lds[131072];

    const int tid  = threadIdx.x;
    const int lane = tid & 63;
    const int wid  = tid >> 6;       // 0..7
    const int wr   = wid >> 2;       // 0..1  -> A rows [wr*128, +128)
    const int wcn  = wid & 3;        // 0..3  -> B cols [wcn*64, +64)

    // T1: bijective XCD swizzle (nwg % 8 == 0 for all shapes), N-tile fastest.
    const int nwg = gridDim.x;
    const int bid = blockIdx.x;
    const int swz = (bid & 7) * (nwg >> 3) + (bid >> 3);
    const int mt = swz / NB, nt = swz % NB;
    const int m0 = mt << 8, n0 = nt << 8;

    // ---- per-thread staging source (row, pre-swizzled chunk), q in {0,1} adds 128 rows
    const int srow = tid >> 2;
    const int scs  = (tid & 3) ^ ((srow >> 1) & 3);
    const unsigned short* gA0 = A  + (size_t)(m0 + srow) * lda + colOff + scs * 8;
    const unsigned short* gA1 = gA0 + (size_t)128 * lda;
    const unsigned short* gB0 = BT + (size_t)(n0 + srow) * K + scs * 8;
    const unsigned short* gB1 = gB0 + (size_t)128 * K;
    const int ldst = wid * 1024;     // + lane*16 implicit

#define STAGE_BLK(dbuf, blkoff, g0, g1, koff)                                            \
    do {                                                                                 \
        __builtin_amdgcn_global_load_lds((const AS1 void*)((g0) + (koff)),               \
                                         (AS3 void*)((dbuf) + (blkoff) + ldst), 16, 0, 0); \
        __builtin_amdgcn_global_load_lds((const AS1 void*)((g1) + (koff)),               \
                                         (AS3 void*)((dbuf) + (blkoff) + 8192 + ldst), 16, 0, 0); \
    } while (0)

    // ---- ds_read offsets (loop-invariant, compile-time indexed)
    int aOff[8], bOff[4];
#pragma unroll
    for (int i = 0; i < 8; ++i) {
        int r = wr * 128 + i * 16 + (lane & 15);
        aOff[i] = r * 64 + ((((lane >> 4) ^ ((r >> 1) & 3))) << 4);
    }
#pragma unroll
    for (int j = 0; j < 4; ++j) {
        int r = wcn * 64 + j * 16 + (lane & 15);
        bOff[j] = r * 64 + ((((lane >> 4) ^ ((r >> 1) & 3))) << 4);
    }

    f32x4 acc[8][4];
#pragma unroll
    for (int i = 0; i < 8; ++i)
#pragma unroll
        for (int j = 0; j < 4; ++j) acc[i][j] = (f32x4)0.f;

    const int KT = K >> 6;

    // ---- prologue: stage tile 0 (Ak0,Bk0,Ak1,Bk1), certify first two blocks
    STAGE_BLK(lds, 0,     gA0, gA1, 0);
    STAGE_BLK(lds, 32768, gB0, gB1, 0);
    STAGE_BLK(lds, 16384, gA0, gA1, 32);
    STAGE_BLK(lds, 49152, gB0, gB1, 32);
    asm volatile("s_waitcnt vmcnt(4)" ::: "memory");
    __builtin_amdgcn_s_barrier();

    for (int t = 0; t < KT; ++t) {
        const char* sbuf = lds + (t & 1) * 65536;
        char* dbuf = lds + ((t + 1) & 1) * 65536;
        const int koff = ((t + 1) << 6);
        const bool st = (t + 1 < KT);
        short8 af[4], bfv[4];

        // ================= P1: kk=0, i=0-3 (reads Ak0+Bk0) =================
#pragma unroll
        for (int i = 0; i < 4; ++i) af[i]  = *(const short8*)(sbuf + aOff[i]);
#pragma unroll
        for (int j = 0; j < 4; ++j) bfv[j] = *(const short8*)(sbuf + 32768 + bOff[j]);
        if (st) STAGE_BLK(dbuf, 0, gA0, gA1, koff);             // Ak0(t+1)
        __builtin_amdgcn_s_barrier();
        asm volatile("s_waitcnt lgkmcnt(0)" ::: "memory");
        __builtin_amdgcn_sched_barrier(0);
        __builtin_amdgcn_s_setprio(1);
#pragma unroll
        for (int i = 0; i < 4; ++i)
#pragma unroll
            for (int j = 0; j < 4; ++j)
                acc[i][j] = __builtin_amdgcn_mfma_f32_16x16x32_bf16(af[i], bfv[j], acc[i][j], 0, 0, 0);
        __builtin_amdgcn_s_setprio(0);
        __builtin_amdgcn_s_barrier();

        // ================= P2: kk=0, i=4-7 (reads Ak0; bfv persists) =======
#pragma unroll
        for (int i = 0; i < 4; ++i) af[i] = *(const short8*)(sbuf + aOff[4 + i]);
        if (st) STAGE_BLK(dbuf, 32768, gB0, gB1, koff);         // Bk0(t+1)
        __builtin_amdgcn_s_barrier();
        asm volatile("s_waitcnt lgkmcnt(0)" ::: "memory");
        __builtin_amdgcn_sched_barrier(0);
        __builtin_amdgcn_s_setprio(1);
#pragma unroll
        for (int i = 0; i < 4; ++i)
#pragma unroll
            for (int j = 0; j < 4; ++j)
                acc[4 + i][j] = __builtin_amdgcn_mfma_f32_16x16x32_bf16(af[i], bfv[j], acc[4 + i][j], 0, 0, 0);
        __builtin_amdgcn_s_setprio(0);
        if (st) { asm volatile("s_waitcnt vmcnt(4)" ::: "memory"); }   // certify Ak1,Bk1(t)
        else    { asm volatile("s_waitcnt vmcnt(0)" ::: "memory"); }
        __builtin_amdgcn_sched_barrier(0);
        __builtin_amdgcn_s_barrier();

        // ================= P3: kk=1, i=0-3 (reads Ak1+Bk1) =================
#pragma unroll
        for (int i = 0; i < 4; ++i) af[i]  = *(const short8*)(sbuf + 16384 + aOff[i]);
#pragma unroll
        for (int j = 0; j < 4; ++j) bfv[j] = *(const short8*)(sbuf + 49152 + bOff[j]);
        if (st) STAGE_BLK(dbuf, 16384, gA0, gA1, koff + 32);    // Ak1(t+1)
        __builtin_amdgcn_s_barrier();
        asm volatile("s_waitcnt lgkmcnt(0)" ::: "memory");
        __builtin_amdgcn_sched_barrier(0);
        __builtin_amdgcn_s_setprio(1);
#pragma unroll
        for (int i = 0; i < 4; ++i)
#pragma unroll
            for (int j = 0; j < 4; ++j)
                acc[i][j] = __builtin_amdgcn_mfma_f32_16x16x32_bf16(af[i], bfv[j], acc[i][j], 0, 0, 0);
        __builtin_amdgcn_s_setprio(0);
        __builtin_amdgcn_s_barrier();

        // ================= P4: kk=1, i=4-7 (reads Ak1; bfv persists) =======
#pragma unroll
        for (int i = 0; i < 4; ++i) af[i] = *(const short8*)(sbuf + 16384 + aOff[4 + i]);
        if (st) STAGE_BLK(dbuf, 49152, gB0, gB1, koff + 32);    // Bk1(t+1)
        __builtin_amdgcn_s_barrier();
        asm volatile("s_waitcnt lgkmcnt(0)" ::: "memory");
        __builtin_amdgcn_sched_barrier(0);
        __builtin_amdgcn_s_setprio(1);
#pragma unroll
        for (int i = 0; i < 4; ++i)
#pragma unroll
            for (int j = 0; j < 4; ++j)
                acc[4 + i][j] = __builtin_amdgcn_mfma_f32_16x16x32_bf16(af[i], bfv[j], acc[4 + i][j], 0, 0, 0);
        __builtin_amdgcn_s_setprio(0);
        if (st) { asm volatile("s_waitcnt vmcnt(4)" ::: "memory"); }   // certify Ak0,Bk0(t+1)
        __builtin_amdgcn_sched_barrier(0);
        __builtin_amdgcn_s_barrier();
    }
#undef STAGE_BLK

    // epilogue: D col = lane&15 (n), row = (lane>>4)*4 + reg (m)  [m89-verified, r1/r2-passed]
    const int mbase = m0 + wr * 128 + (lane >> 4) * 4;
    const int nbase = n0 + wcn * 64 + (lane & 15);

    if (MODE == 2) {
        float bv[4], wv[4];
#pragma unroll
        for (int j = 0; j < 4; ++j) {
            int ncol = nbase + j * 16;
            bv[j] = bias[ncol];
            wv[j] = w2[ncol];
        }
#pragma unroll
        for (int i = 0; i < 8; ++i) {
#pragma unroll
            for (int r = 0; r < 4; ++r) {
                float p = 0.f;
#pragma unroll
                for (int j = 0; j < 4; ++j) {
                    float v = fmaxf(acc[i][j][r] + bv[j], 0.f);
                    p += v * wv[j];
                }
                p += __shfl_xor(p, 1);
                p += __shfl_xor(p, 2);
                p += __shfl_xor(p, 4);
                p += __shfl_xor(p, 8);
                if ((lane & 15) == 0) {
                    atomicAdd(&ydot[mbase + i * 16 + r], p);
                }
            }
        }
    } else {
        float bv[4];
#pragma unroll
        for (int j = 0; j < 4; ++j) bv[j] = bias[nbase + j * 16];
#pragma unroll
        for (int i = 0; i < 8; ++i) {
#pragma unroll
            for (int j = 0; j < 4; ++j) {
                int ncol = nbase + j * 16;
#pragma unroll
                for (int r = 0; r < 4; ++r) {
                    float v = acc[i][j][r] + bv[j];
                    if (MODE == 0) v = fmaxf(v, 0.f);
                    size_t idx = (size_t)(mbase + i * 16 + r) * Ncols + ncol;
                    if (MODE == 1) Cf32[idx] = v;
                    Cbf[idx] = f2bf(v);
                }
            }
        }
    }
}

// ---------------- launch ----------------

extern "C" void kernel_launch(void* const* d_in, const int* in_sizes, int n_in,
                              void* d_out, int out_size, void* d_ws, size_t ws_size,
                              hipStream_t stream) {
    const float* X  = (const float*)d_in[0];
    const int*  TR  = (const int*)d_in[1];
    const float* W0 = (const float*)d_in[2];  const float* b0 = (const float*)d_in[3];
    const float* W1 = (const float*)d_in[4];  const float* b1 = (const float*)d_in[5];
    const float* W2 = (const float*)d_in[6];  const float* b2 = (const float*)d_in[7];
    const float* A0 = (const float*)d_in[8];  const float* a0 = (const float*)d_in[9];
    const float* A1 = (const float*)d_in[10]; const float* a1 = (const float*)d_in[11];
    const float* A2 = (const float*)d_in[12];
    const float* C0 = (const float*)d_in[13]; const float* c0 = (const float*)d_in[14];
    const float* C1 = (const float*)d_in[15]; const float* c1 = (const float*)d_in[16];
    const float* C2 = (const float*)d_in[17];

    float* y_out   = (float*)d_out;           // [N]
    float* out_out = (float*)d_out + NSAMP;   // [N][512] fp32

    char* ws = (char*)d_ws;
    size_t off = 0;
    auto alloc = [&](size_t bytes) -> char* {
        char* p = ws + off;
        off += (bytes + 255) & ~(size_t)255;
        return p;
    };
    unsigned short* Xb  = (unsigned short*)alloc((size_t)NSAMP * 512 * 2);
    unsigned short* H1b = (unsigned short*)alloc((size_t)NSAMP * 1024 * 2);
    unsigned short* H2b = (unsigned short*)alloc((size_t)NSAMP * 1024 * 2);
    unsigned short* OUTb = H1b;                       // H1b dead after L1 GEMM
    unsigned short* R01  = H2b;                       // [N][1024]: cols 0-511 expert0, 512-1023 expert1
    unsigned short* W0T = (unsigned short*)alloc(512 * 1024 * 2);
    unsigned short* W1T = (unsigned short*)alloc(1024 * 1024 * 2);
    unsigned short* W2T = (unsigned short*)alloc(1024 * 512 * 2);
    unsigned short* RT0 = (unsigned short*)alloc(1024 * 512 * 2);   // [A0T; C0T]
    unsigned short* A1T = (unsigned short*)alloc(512 * 512 * 2);
    unsigned short* C1T = (unsigned short*)alloc(512 * 512 * 2);
    float* bcat = (float*)alloc(1024 * 4);
    float* y0 = (float*)alloc(NSAMP * 4);
    float* y1 = (float*)alloc(NSAMP * 4);

    // prep
    k_convert_bf16<<<(NSAMP * 512 / 8 + 255) / 256, 256, 0, stream>>>(X, Xb, NSAMP * 512 / 8);
    PrepArgs pa;
    pa.W0 = W0; pa.W1 = W1; pa.W2 = W2; pa.A0 = A0; pa.C0 = C0; pa.A1 = A1; pa.C1 = C1;
    pa.a0v = a0; pa.c0v = c0;
    pa.W0T = W0T; pa.W1T = W1T; pa.W2T = W2T; pa.RT0 = RT0; pa.A1T = A1T; pa.C1T = C1T;
    pa.bcat = bcat; pa.y0 = y0; pa.y1 = y1;
    k_prep<<<(3277824 + 255) / 256, 256, 0, stream>>>(pa);

    const int MB = NSAMP / 256;   // 256 M-tiles

    // shared MLP
    k_gemm256<0><<<MB * 4, 512, 0, stream>>>(Xb, 512, 0, W0T, b0, H1b, nullptr, nullptr, nullptr, 1024, 512, 4);
    k_gemm256<0><<<MB * 4, 512, 0, stream>>>(H1b, 1024, 0, W1T, b1, H2b, nullptr, nullptr, nullptr, 1024, 1024, 4);
    k_gemm256<1><<<MB * 2, 512, 0, stream>>>(H2b, 1024, 0, W2T, b2, OUTb, out_out, nullptr, nullptr, 512, 1024, 2);

    // risk nets layer 0, both experts merged (N=1024)
    k_gemm256<0><<<MB * 4, 512, 0, stream>>>(OUTb, 512, 0, RT0, bcat, R01, nullptr, nullptr, nullptr, 1024, 512, 4);

    // risk nets layer 1 + fused 512->1 dot
    k_gemm256<2><<<MB * 2, 512, 0, stream>>>(R01, 1024, 0,   A1T, a1, nullptr, nullptr, A2, y0, 512, 512, 2);
    k_gemm256<2><<<MB * 2, 512, 0, stream>>>(R01, 1024, 512, C1T, c1, nullptr, nullptr, C2, y1, 512, 512, 2);

    // per-sample expert selection
    k_select<<<(NSAMP + 255) / 256, 256, 0, stream>>>(y0, y1, TR, y_out, NSAMP);
}